// Round 4
// baseline (131.080 us; speedup 1.0000x reference)
//
#include <hip/hip_runtime.h>
#include <hip/hip_bf16.h>

// Volume-rendering composite:
//   dd = deltas * density                       [rays, 128]
//   T_i = exp(-sum_{j<i} dd_j)                  (exclusive cumsum)
//   w_i = (1 - exp(-dd_i)) * T_i = T_i - T_{i+1}
//   out[r, c] = sum_i w_i * rgb[r, i, c]        [rays, 3]
//
// Wave = 2 rays (32-lane segments). Segment-lane l owns samples 4l..4l+3:
// every global load is an aligned 16B dwordx4. All data is touched exactly
// once -> non-temporal loads/stores (nt modifier) to skip cache allocation.
// NOTE: __builtin_nontemporal_load needs a clang ext_vector type, not
// HIP_vector_type (struct) — hence v4f below.

typedef float v4f __attribute__((ext_vector_type(4)));

__global__ __launch_bounds__(256) void composite_kernel(
    const v4f* __restrict__ rgb4,     // [rays * 96]  (rays,128,3) as float4
    const v4f* __restrict__ density4, // [rays * 32]
    const v4f* __restrict__ deltas4,  // [rays * 32]
    float* __restrict__ out,          // [rays, 3]
    int num_rays)
{
    const int lane = threadIdx.x & 63;
    const int seg  = lane >> 5;                       // which ray of the wave
    const int sl   = lane & 31;                       // segment-local lane
    const int wave = threadIdx.x >> 6;                // 0..3
    const int ray  = (blockIdx.x * 4 + wave) * 2 + seg;
    if (ray >= num_rays) return;

    // --- independent streaming loads, issued up front ---
    const v4f de = __builtin_nontemporal_load(density4 + (size_t)ray * 32 + sl);
    const v4f dl = __builtin_nontemporal_load(deltas4  + (size_t)ray * 32 + sl);
    const v4f* r4 = rgb4 + (size_t)ray * 96 + sl * 3;
    const v4f q0 = __builtin_nontemporal_load(r4 + 0);   // r0 g0 b0 r1
    const v4f q1 = __builtin_nontemporal_load(r4 + 1);   // g1 b1 r2 g2
    const v4f q2 = __builtin_nontemporal_load(r4 + 2);   // b2 r3 g3 b3

    const float dd0 = de.x * dl.x;
    const float dd1 = de.y * dl.y;
    const float dd2 = de.z * dl.z;
    const float dd3 = de.w * dl.w;
    const float local = dd0 + dd1 + dd2 + dd3;

    // --- segmented inclusive scan of per-lane sums (32-lane segment) ---
    float s = local;
#pragma unroll
    for (int off = 1; off < 32; off <<= 1) {
        float v = __shfl_up(s, off, 64);   // src = lane - off, in-segment when sl >= off
        if (sl >= off) s += v;
    }
    const float excl = s - local;          // sum of dd over samples < 4*sl
    const float c0 = excl + dd0;
    const float c1 = c0 + dd1;
    const float c2 = c1 + dd2;
    const float c3 = c2 + dd3;

    const float Te = __expf(-excl);
    const float T0 = __expf(-c0);
    const float T1 = __expf(-c1);
    const float T2 = __expf(-c2);
    const float T3 = __expf(-c3);
    const float w0 = Te - T0;
    const float w1 = T0 - T1;
    const float w2 = T1 - T2;
    const float w3 = T2 - T3;

    float rr = w0 * q0.x + w1 * q0.w + w2 * q1.z + w3 * q2.y;
    float gg = w0 * q0.y + w1 * q1.x + w2 * q1.w + w3 * q2.z;
    float bb = w0 * q0.z + w1 * q1.y + w2 * q2.x + w3 * q2.w;

    // --- segment reduce (xor butterfly stays within the 32-lane segment) ---
#pragma unroll
    for (int off = 16; off; off >>= 1) {
        rr += __shfl_xor(rr, off, 64);
        gg += __shfl_xor(gg, off, 64);
        bb += __shfl_xor(bb, off, 64);
    }

    if (sl == 0) {
        float* o = out + (size_t)ray * 3;
        __builtin_nontemporal_store(rr, o + 0);
        __builtin_nontemporal_store(gg, o + 1);
        __builtin_nontemporal_store(bb, o + 2);
    }
}

extern "C" void kernel_launch(void* const* d_in, const int* in_sizes, int n_in,
                              void* d_out, int out_size, void* d_ws, size_t ws_size,
                              hipStream_t stream) {
    const v4f* rgb     = (const v4f*)d_in[0];
    const v4f* density = (const v4f*)d_in[1];
    const v4f* deltas  = (const v4f*)d_in[2];
    float* out = (float*)d_out;

    const int num_rays = in_sizes[1] / 128;            // 262144
    const int rays_per_block = 8;                      // 4 waves x 2 rays
    const int grid = (num_rays + rays_per_block - 1) / rays_per_block;

    composite_kernel<<<grid, 256, 0, stream>>>(rgb, density, deltas, out, num_rays);
}

// Round 5
// 110.606 us; speedup vs baseline: 1.1851x; 1.1851x over previous
//
#include <hip/hip_runtime.h>
#include <hip/hip_bf16.h>

// Volume-rendering composite:
//   dd = deltas * density                       [rays, 128]
//   T_i = exp(-sum_{j<i} dd_j)                  (exclusive cumsum)
//   w_i = (1 - exp(-dd_i)) * T_i = T_i - T_{i+1}
//   out[r, c] = sum_i w_i * rgb[r, i, c]        [rays, 3]
//
// Wave = 2 segments of 32 lanes; each segment processes TWO rays (A,B) to
// double memory-level parallelism: 10 independent dwordx4 loads (160 B) in
// flight per lane before any dependent compute. Segment-lane l owns samples
// 4l..4l+3 of each ray. No non-temporal hints (R4: nt regressed 12% — the
// strided rgb instructions depend on L2 line reuse).

__global__ __launch_bounds__(256) void composite_kernel(
    const float4* __restrict__ rgb4,     // [rays * 96]  (rays,128,3) as float4
    const float4* __restrict__ density4, // [rays * 32]
    const float4* __restrict__ deltas4,  // [rays * 32]
    float* __restrict__ out,             // [rays, 3]
    int num_rays)
{
    const int lane = threadIdx.x & 63;
    const int seg  = lane >> 5;
    const int sl   = lane & 31;
    const int wave = threadIdx.x >> 6;                // 0..3
    const int segid = (blockIdx.x * 4 + wave) * 2 + seg;
    const int rayA = segid * 2;
    const int rayB = rayA + 1;
    if (rayB >= num_rays + 1) return;                 // rays are multiple of 16 anyway

    // --- issue all 10 independent loads up front ---
    const float4 deA = density4[(size_t)rayA * 32 + sl];
    const float4 dlA = deltas4 [(size_t)rayA * 32 + sl];
    const float4 deB = density4[(size_t)rayB * 32 + sl];
    const float4 dlB = deltas4 [(size_t)rayB * 32 + sl];
    const float4* rA = rgb4 + (size_t)rayA * 96 + sl * 3;
    const float4* rB = rgb4 + (size_t)rayB * 96 + sl * 3;
    const float4 a0 = rA[0], a1 = rA[1], a2 = rA[2];
    const float4 b0 = rB[0], b1 = rB[1], b2 = rB[2];

    // --- per-lane delta*density ---
    const float dA0 = deA.x * dlA.x, dA1 = deA.y * dlA.y,
                dA2 = deA.z * dlA.z, dA3 = deA.w * dlA.w;
    const float dB0 = deB.x * dlB.x, dB1 = deB.y * dlB.y,
                dB2 = deB.z * dlB.z, dB3 = deB.w * dlB.w;
    const float localA = dA0 + dA1 + dA2 + dA3;
    const float localB = dB0 + dB1 + dB2 + dB3;

    // --- two interleaved segmented inclusive scans (32-lane segments) ---
    float sA = localA, sB = localB;
#pragma unroll
    for (int off = 1; off < 32; off <<= 1) {
        float vA = __shfl_up(sA, off, 64);
        float vB = __shfl_up(sB, off, 64);
        if (sl >= off) { sA += vA; sB += vB; }
    }
    const float exA = sA - localA;
    const float exB = sB - localB;

    const float cA0 = exA + dA0, cA1 = cA0 + dA1, cA2 = cA1 + dA2, cA3 = cA2 + dA3;
    const float cB0 = exB + dB0, cB1 = cB0 + dB1, cB2 = cB1 + dB2, cB3 = cB2 + dB3;

    const float TAe = __expf(-exA), TA0 = __expf(-cA0), TA1 = __expf(-cA1),
                TA2 = __expf(-cA2), TA3 = __expf(-cA3);
    const float TBe = __expf(-exB), TB0 = __expf(-cB0), TB1 = __expf(-cB1),
                TB2 = __expf(-cB2), TB3 = __expf(-cB3);

    const float wA0 = TAe - TA0, wA1 = TA0 - TA1, wA2 = TA1 - TA2, wA3 = TA2 - TA3;
    const float wB0 = TBe - TB0, wB1 = TB0 - TB1, wB2 = TB1 - TB2, wB3 = TB2 - TB3;

    // --- weighted rgb partials (layouts: q0 = r0 g0 b0 r1; q1 = g1 b1 r2 g2; q2 = b2 r3 g3 b3) ---
    float rrA = wA0 * a0.x + wA1 * a0.w + wA2 * a1.z + wA3 * a2.y;
    float ggA = wA0 * a0.y + wA1 * a1.x + wA2 * a1.w + wA3 * a2.z;
    float bbA = wA0 * a0.z + wA1 * a1.y + wA2 * a2.x + wA3 * a2.w;
    float rrB = wB0 * b0.x + wB1 * b0.w + wB2 * b1.z + wB3 * b2.y;
    float ggB = wB0 * b0.y + wB1 * b1.x + wB2 * b1.w + wB3 * b2.z;
    float bbB = wB0 * b0.z + wB1 * b1.y + wB2 * b2.x + wB3 * b2.w;

    // --- segment reduce (xor butterfly, segment-closed for off<32) ---
#pragma unroll
    for (int off = 16; off; off >>= 1) {
        rrA += __shfl_xor(rrA, off, 64);
        ggA += __shfl_xor(ggA, off, 64);
        bbA += __shfl_xor(bbA, off, 64);
        rrB += __shfl_xor(rrB, off, 64);
        ggB += __shfl_xor(ggB, off, 64);
        bbB += __shfl_xor(bbB, off, 64);
    }

    if (sl == 0) {
        float* oA = out + (size_t)rayA * 3;
        oA[0] = rrA; oA[1] = ggA; oA[2] = bbA;
        float* oB = out + (size_t)rayB * 3;
        oB[0] = rrB; oB[1] = ggB; oB[2] = bbB;
    }
}

extern "C" void kernel_launch(void* const* d_in, const int* in_sizes, int n_in,
                              void* d_out, int out_size, void* d_ws, size_t ws_size,
                              hipStream_t stream) {
    const float4* rgb     = (const float4*)d_in[0];
    const float4* density = (const float4*)d_in[1];
    const float4* deltas  = (const float4*)d_in[2];
    float* out = (float*)d_out;

    const int num_rays = in_sizes[1] / 128;            // 262144
    const int rays_per_block = 16;                     // 4 waves x 2 segments x 2 rays
    const int grid = (num_rays + rays_per_block - 1) / rays_per_block;

    composite_kernel<<<grid, 256, 0, stream>>>(rgb, density, deltas, out, num_rays);
}